// Round 7
// baseline (128.090 us; speedup 1.0000x reference)
//
#include <hip/hip_runtime.h>
#include <hip/hip_bf16.h>

// SmoothLDDTLoss: b=2, n=4096
// inputs: pred_coords f32[2,4096,3], true_coords f32[2,4096,3],
//         is_dna i32[2,4096], is_rna i32[2,4096], coords_mask i32[2,4096]
// output: scalar f32 = 1 - mean_b(lddt_b)
//
// sigma(.5-d)+sigma(1-d)+sigma(2-d)+sigma(4-d) = t*Q'(t)/Q(t), t=e^{-d} (exact).
// Coords pre-scaled by log2(e) so t = exp2(-|dt_s-dp_s|) is a raw v_exp_f32.
// Symmetry via cyclic half-shell: o=(j-i) mod n, o in [1, n/2], weight 1/2 at
// o==n/2 -> exactly half the i!=j sum for BOTH eps-sum and count.
// o-range split across 2 blocks per strip for occupancy (2048 uniform blocks).
// Final division fused into the last finishing block (device-scope counter).

#define NRES 4096
#define NBATCH 2
#define TI 8
#define NTILE 9            // o in [0, 2304) covers [1, 2048+TI-1]
#define OSPLIT 5           // block osel=0: tiles [0,5); osel=1: tiles [5,9)
#define NBLOCKS 2048       // 512 strips * 2 osel * 2 batch

// scaled cutoffs: 15*log2(e), 30*log2(e)
#define CUT15 21.6404256133f
#define CUT30 43.2808512267f

// Q coefficients: elementary symmetric polys of {e^0.5, e^1, e^2, e^4}
#define S1 66.35420923f
#define S2 678.60880385f
#define S3 2039.58217570f
#define S4 1808.04241445f
// Q'(t)/4 coefficients
#define QP1 16.58855231f
#define QP2 339.30440193f
#define QP3 1529.68663177f
#define QP4 1808.04241445f

#define LOG2E 1.44269504089f

__global__ void pack_kernel(const float* __restrict__ pred,
                            const float* __restrict__ truec,
                            const int* __restrict__ dna,
                            const int* __restrict__ rna,
                            const int* __restrict__ cm,
                            float4* __restrict__ tp,
                            float4* __restrict__ pp)
{
    int idx = blockIdx.x * 256 + threadIdx.x;
    if (idx >= NRES * NBATCH) return;
    float nuc = ((dna[idx] | rna[idx]) != 0) ? 1.0f : 0.0f;
    float cmf = (cm[idx] != 0) ? 1.0f : 0.0f;
    tp[idx] = make_float4(truec[3*idx+0]*LOG2E, truec[3*idx+1]*LOG2E, truec[3*idx+2]*LOG2E, nuc);
    pp[idx] = make_float4(pred[3*idx+0]*LOG2E,  pred[3*idx+1]*LOG2E,  pred[3*idx+2]*LOG2E,  cmf);
}

// MODE 0: clean interior tile; MODE 1: lower edge (need o-r>=1);
// MODE 2: upper edge (need o-r<=2048, half weight at exactly 2048)
#define PAIR_LOOP(MODE)                                                     \
    _Pragma("unroll")                                                       \
    for (int r = 0; r < TI; ++r) {                                          \
        float dx = tix[r] - t4.x, dy = tiy[r] - t4.y, dz = tiz[r] - t4.z;   \
        float dt = __builtin_amdgcn_sqrtf(dx*dx + dy*dy + dz*dz);           \
        float ex = pix[r] - p4.x, ey = piy[r] - p4.y, ez = piz[r] - p4.z;   \
        float dp = __builtin_amdgcn_sqrtf(ex*ex + ey*ey + ez*ez);           \
        float cutoff = nucj ? cHi[r] : cLo[r];                              \
        float mf = (dt < cutoff) ? wj : 0.0f;                               \
        if (MODE == 1) mf = (o >= r + 1) ? mf : 0.0f;                       \
        if (MODE == 2) { int d = o - r;                                     \
            mf = (d <= 2048) ? mf : 0.0f;                                   \
            mf = (d == 2048) ? 0.5f * mf : mf; }                            \
        float t = __builtin_amdgcn_exp2f(-fabsf(dt - dp));                  \
        float Q  = 1.0f + t*(S1 + t*(S2 + t*(S3 + t*S4)));                  \
        float Qp = QP1 + t*(QP2 + t*(QP3 + t*QP4));                         \
        float rq = __builtin_amdgcn_rcpf(Q);                                \
        s += mf * ((t * Qp) * rq);                                          \
        c += mf;                                                            \
    }

__launch_bounds__(256, 8)
__global__ void lddt_main(const float4* __restrict__ tp,
                          const float4* __restrict__ pp,
                          float* __restrict__ acc,          // [0..1] sums, [2..3] counts
                          unsigned int* __restrict__ done,  // block-completion counter
                          float* __restrict__ out)
{
    const int b    = blockIdx.z;
    const int osel = blockIdx.y;
    const int i0   = blockIdx.x * TI;
    const int base = b * NRES;
    const int tid  = threadIdx.x;

    const int ob = osel ? OSPLIT : 0;
    const int oe = osel ? NTILE  : OSPLIT;

    float tix[TI], tiy[TI], tiz[TI];
    float pix[TI], piy[TI], piz[TI];
    float cHi[TI], cLo[TI];
    #pragma unroll
    for (int r = 0; r < TI; ++r) {
        float4 t4 = tp[base + i0 + r];
        float4 p4 = pp[base + i0 + r];
        tix[r] = t4.x; tiy[r] = t4.y; tiz[r] = t4.z;
        pix[r] = p4.x; piy[r] = p4.y; piz[r] = p4.z;
        bool cmi  = (p4.w != 0.0f);
        bool nuci = (t4.w != 0.0f);
        cHi[r] = cmi ? (nuci ? CUT30 : CUT15) : -1.0f;
        cLo[r] = cmi ? CUT15 : -1.0f;
    }

    float s = 0.0f, c = 0.0f;

    float4 t4 = tp[base + ((i0 + ob * 256 + tid) & (NRES - 1))];
    float4 p4 = pp[base + ((i0 + ob * 256 + tid) & (NRES - 1))];

    #pragma unroll 1
    for (int tl = ob; tl < oe; ++tl) {
        // prefetch next tile (last iter re-fetches first tile; always in-bounds)
        const int on = ((tl + 1 < oe) ? tl + 1 : ob) * 256 + tid;
        const int jn = (i0 + on) & (NRES - 1);
        float4 t4n = tp[base + jn];
        float4 p4n = pp[base + jn];

        const float wj   = p4.w;               // cm_j as 1.0/0.0
        const bool  nucj = (t4.w != 0.0f);
        const int   o    = tl * 256 + tid;     // cyclic offset j-i

        if (tl == 0)            { PAIR_LOOP(1) }
        else if (tl == NTILE-1) { PAIR_LOOP(2) }
        else                    { PAIR_LOOP(0) }

        t4 = t4n; p4 = p4n;
    }

    // wave (64-lane) reduction
    #pragma unroll
    for (int off = 32; off > 0; off >>= 1) {
        s += __shfl_down(s, off, 64);
        c += __shfl_down(c, off, 64);
    }

    __shared__ float red_s[4];
    __shared__ float red_c[4];
    const int wid  = tid >> 6;
    const int lane = tid & 63;
    if (lane == 0) { red_s[wid] = s; red_c[wid] = c; }
    __syncthreads();

    if (tid == 0) {
        float ts = red_s[0] + red_s[1] + red_s[2] + red_s[3];
        float tc = red_c[0] + red_c[1] + red_c[2] + red_c[3];
        atomicAdd(&acc[b], ts);
        atomicAdd(&acc[NBATCH + b], tc);
        __threadfence();
        unsigned int old = atomicAdd(done, 1u);
        if (old == NBLOCKS - 1u) {
            float a0 = __hip_atomic_load(&acc[0], __ATOMIC_ACQUIRE, __HIP_MEMORY_SCOPE_AGENT);
            float a1 = __hip_atomic_load(&acc[1], __ATOMIC_ACQUIRE, __HIP_MEMORY_SCOPE_AGENT);
            float c0 = __hip_atomic_load(&acc[2], __ATOMIC_ACQUIRE, __HIP_MEMORY_SCOPE_AGENT);
            float c1 = __hip_atomic_load(&acc[3], __ATOMIC_ACQUIRE, __HIP_MEMORY_SCOPE_AGENT);
            float l0 = a0 / fmaxf(c0, 0.5f);
            float l1 = a1 / fmaxf(c1, 0.5f);
            out[0] = 1.0f - 0.5f * (l0 + l1);
        }
    }
}

extern "C" void kernel_launch(void* const* d_in, const int* in_sizes, int n_in,
                              void* d_out, int out_size, void* d_ws, size_t ws_size,
                              hipStream_t stream) {
    const float* pred  = (const float*)d_in[0];
    const float* truec = (const float*)d_in[1];
    const int*   dna   = (const int*)d_in[2];
    const int*   rna   = (const int*)d_in[3];
    const int*   cmask = (const int*)d_in[4];
    float* out = (float*)d_out;

    char* ws = (char*)d_ws;
    float*        acc  = (float*)ws;              // 4 floats
    unsigned int* done = (unsigned int*)(ws + 64);
    float4* tp = (float4*)(ws + 1024);            // 2*4096*16 B
    float4* pp = (float4*)(ws + 1024 + NBATCH*NRES*16);

    (void)hipMemsetAsync(ws, 0, 128, stream);     // acc + done

    pack_kernel<<<(NRES*NBATCH + 255)/256, 256, 0, stream>>>(pred, truec, dna, rna, cmask, tp, pp);

    dim3 grid(NRES / TI, 2, NBATCH);
    lddt_main<<<grid, 256, 0, stream>>>(tp, pp, acc, done, out);
}

// Round 8
// 81.659 us; speedup vs baseline: 1.5686x; 1.5686x over previous
//
#include <hip/hip_runtime.h>
#include <hip/hip_bf16.h>

// SmoothLDDTLoss: b=2, n=4096
// inputs: pred_coords f32[2,4096,3], true_coords f32[2,4096,3],
//         is_dna i32[2,4096], is_rna i32[2,4096], coords_mask i32[2,4096]
// output: scalar f32 = 1 - mean_b(lddt_b)
//
// sigma(.5-d)+sigma(1-d)+sigma(2-d)+sigma(4-d) = t*Q'(t)/Q(t), t=e^{-d} (exact).
// Coords pre-scaled by log2(e) so t = exp2(-|dt_s-dp_s|) is a raw v_exp_f32.
// Symmetry via cyclic half-shell: o=(j-i) mod n, o in [1, n/2], weight 1/2 at
// o==n/2 -> exactly half the i!=j sum for BOTH eps-sum and count.
// o-range split across 2 blocks per strip (2048 uniform blocks).
// Final division fused into the last finishing block (device-scope counter).
// NOTE: launch_bounds must stay (256,4): the (256,8) 64-VGPR cap spills the
// 8-row strip state to scratch (188 MB of HBM writes, 3x slowdown — round 7).

#define NRES 4096
#define NBATCH 2
#define TI 8
#define NTILE 9            // o in [0, 2304) covers [1, 2048+TI-1]
#define OSPLIT 5           // block osel=0: tiles [0,5); osel=1: tiles [5,9)
#define NBLOCKS 2048       // 512 strips * 2 osel * 2 batch

// scaled cutoffs: 15*log2(e), 30*log2(e)
#define CUT15 21.6404256133f
#define CUT30 43.2808512267f

// Q coefficients: elementary symmetric polys of {e^0.5, e^1, e^2, e^4}
#define S1 66.35420923f
#define S2 678.60880385f
#define S3 2039.58217570f
#define S4 1808.04241445f
// Q'(t)/4 coefficients
#define QP1 16.58855231f
#define QP2 339.30440193f
#define QP3 1529.68663177f
#define QP4 1808.04241445f

#define LOG2E 1.44269504089f

__global__ void pack_kernel(const float* __restrict__ pred,
                            const float* __restrict__ truec,
                            const int* __restrict__ dna,
                            const int* __restrict__ rna,
                            const int* __restrict__ cm,
                            float4* __restrict__ tp,
                            float4* __restrict__ pp)
{
    int idx = blockIdx.x * 256 + threadIdx.x;
    if (idx >= NRES * NBATCH) return;
    float nuc = ((dna[idx] | rna[idx]) != 0) ? 1.0f : 0.0f;
    float cmf = (cm[idx] != 0) ? 1.0f : 0.0f;
    tp[idx] = make_float4(truec[3*idx+0]*LOG2E, truec[3*idx+1]*LOG2E, truec[3*idx+2]*LOG2E, nuc);
    pp[idx] = make_float4(pred[3*idx+0]*LOG2E,  pred[3*idx+1]*LOG2E,  pred[3*idx+2]*LOG2E,  cmf);
}

// MODE 0: clean interior tile; MODE 1: lower edge (need o-r>=1);
// MODE 2: upper edge (need o-r<=2048, half weight at exactly 2048)
#define PAIR_LOOP(MODE)                                                     \
    _Pragma("unroll")                                                       \
    for (int r = 0; r < TI; ++r) {                                          \
        float dx = tix[r] - t4.x, dy = tiy[r] - t4.y, dz = tiz[r] - t4.z;   \
        float dt = __builtin_amdgcn_sqrtf(dx*dx + dy*dy + dz*dz);           \
        float ex = pix[r] - p4.x, ey = piy[r] - p4.y, ez = piz[r] - p4.z;   \
        float dp = __builtin_amdgcn_sqrtf(ex*ex + ey*ey + ez*ez);           \
        float cutoff = nucj ? cHi[r] : cLo[r];                              \
        float mf = (dt < cutoff) ? wj : 0.0f;                               \
        if (MODE == 1) mf = (o >= r + 1) ? mf : 0.0f;                       \
        if (MODE == 2) { int d = o - r;                                     \
            mf = (d <= 2048) ? mf : 0.0f;                                   \
            mf = (d == 2048) ? 0.5f * mf : mf; }                            \
        float t = __builtin_amdgcn_exp2f(-fabsf(dt - dp));                  \
        float Q  = 1.0f + t*(S1 + t*(S2 + t*(S3 + t*S4)));                  \
        float Qp = QP1 + t*(QP2 + t*(QP3 + t*QP4));                         \
        float rq = __builtin_amdgcn_rcpf(Q);                                \
        s += mf * ((t * Qp) * rq);                                          \
        c += mf;                                                            \
    }

__launch_bounds__(256, 4)
__global__ void lddt_main(const float4* __restrict__ tp,
                          const float4* __restrict__ pp,
                          float* __restrict__ acc,          // [0..1] sums, [2..3] counts
                          unsigned int* __restrict__ done,  // block-completion counter
                          float* __restrict__ out)
{
    const int b    = blockIdx.z;
    const int osel = blockIdx.y;
    const int i0   = blockIdx.x * TI;
    const int base = b * NRES;
    const int tid  = threadIdx.x;

    const int ob = osel ? OSPLIT : 0;
    const int oe = osel ? NTILE  : OSPLIT;

    float tix[TI], tiy[TI], tiz[TI];
    float pix[TI], piy[TI], piz[TI];
    float cHi[TI], cLo[TI];
    #pragma unroll
    for (int r = 0; r < TI; ++r) {
        float4 t4 = tp[base + i0 + r];
        float4 p4 = pp[base + i0 + r];
        tix[r] = t4.x; tiy[r] = t4.y; tiz[r] = t4.z;
        pix[r] = p4.x; piy[r] = p4.y; piz[r] = p4.z;
        bool cmi  = (p4.w != 0.0f);
        bool nuci = (t4.w != 0.0f);
        cHi[r] = cmi ? (nuci ? CUT30 : CUT15) : -1.0f;
        cLo[r] = cmi ? CUT15 : -1.0f;
    }

    float s = 0.0f, c = 0.0f;

    float4 t4 = tp[base + ((i0 + ob * 256 + tid) & (NRES - 1))];
    float4 p4 = pp[base + ((i0 + ob * 256 + tid) & (NRES - 1))];

    #pragma unroll 1
    for (int tl = ob; tl < oe; ++tl) {
        // prefetch next tile (last iter re-fetches first tile; always in-bounds)
        const int on = ((tl + 1 < oe) ? tl + 1 : ob) * 256 + tid;
        const int jn = (i0 + on) & (NRES - 1);
        float4 t4n = tp[base + jn];
        float4 p4n = pp[base + jn];

        const float wj   = p4.w;               // cm_j as 1.0/0.0
        const bool  nucj = (t4.w != 0.0f);
        const int   o    = tl * 256 + tid;     // cyclic offset j-i

        if (tl == 0)            { PAIR_LOOP(1) }
        else if (tl == NTILE-1) { PAIR_LOOP(2) }
        else                    { PAIR_LOOP(0) }

        t4 = t4n; p4 = p4n;
    }

    // wave (64-lane) reduction
    #pragma unroll
    for (int off = 32; off > 0; off >>= 1) {
        s += __shfl_down(s, off, 64);
        c += __shfl_down(c, off, 64);
    }

    __shared__ float red_s[4];
    __shared__ float red_c[4];
    const int wid  = tid >> 6;
    const int lane = tid & 63;
    if (lane == 0) { red_s[wid] = s; red_c[wid] = c; }
    __syncthreads();

    if (tid == 0) {
        float ts = red_s[0] + red_s[1] + red_s[2] + red_s[3];
        float tc = red_c[0] + red_c[1] + red_c[2] + red_c[3];
        atomicAdd(&acc[b], ts);
        atomicAdd(&acc[NBATCH + b], tc);
        __threadfence();
        unsigned int old = atomicAdd(done, 1u);
        if (old == NBLOCKS - 1u) {
            float a0 = __hip_atomic_load(&acc[0], __ATOMIC_ACQUIRE, __HIP_MEMORY_SCOPE_AGENT);
            float a1 = __hip_atomic_load(&acc[1], __ATOMIC_ACQUIRE, __HIP_MEMORY_SCOPE_AGENT);
            float c0 = __hip_atomic_load(&acc[2], __ATOMIC_ACQUIRE, __HIP_MEMORY_SCOPE_AGENT);
            float c1 = __hip_atomic_load(&acc[3], __ATOMIC_ACQUIRE, __HIP_MEMORY_SCOPE_AGENT);
            float l0 = a0 / fmaxf(c0, 0.5f);
            float l1 = a1 / fmaxf(c1, 0.5f);
            out[0] = 1.0f - 0.5f * (l0 + l1);
        }
    }
}

extern "C" void kernel_launch(void* const* d_in, const int* in_sizes, int n_in,
                              void* d_out, int out_size, void* d_ws, size_t ws_size,
                              hipStream_t stream) {
    const float* pred  = (const float*)d_in[0];
    const float* truec = (const float*)d_in[1];
    const int*   dna   = (const int*)d_in[2];
    const int*   rna   = (const int*)d_in[3];
    const int*   cmask = (const int*)d_in[4];
    float* out = (float*)d_out;

    char* ws = (char*)d_ws;
    float*        acc  = (float*)ws;              // 4 floats
    unsigned int* done = (unsigned int*)(ws + 64);
    float4* tp = (float4*)(ws + 1024);            // 2*4096*16 B
    float4* pp = (float4*)(ws + 1024 + NBATCH*NRES*16);

    (void)hipMemsetAsync(ws, 0, 128, stream);     // acc + done

    pack_kernel<<<(NRES*NBATCH + 255)/256, 256, 0, stream>>>(pred, truec, dna, rna, cmask, tp, pp);

    dim3 grid(NRES / TI, 2, NBATCH);
    lddt_main<<<grid, 256, 0, stream>>>(tp, pp, acc, done, out);
}

// Round 9
// 54.308 us; speedup vs baseline: 2.3586x; 1.5036x over previous
//
#include <hip/hip_runtime.h>
#include <hip/hip_bf16.h>

// SmoothLDDTLoss: b=2, n=4096
// inputs: pred_coords f32[2,4096,3], true_coords f32[2,4096,3],
//         is_dna i32[2,4096], is_rna i32[2,4096], coords_mask i32[2,4096]
// output: scalar f32 = 1 - mean_b(lddt_b)
//
// sigma(.5-d)+sigma(1-d)+sigma(2-d)+sigma(4-d) = t*Q'(t)/Q(t), t=e^{-d} (exact).
// Coords pre-scaled by log2(e) so t = exp2(-|dt_s-dp_s|) is a raw v_exp_f32.
// Symmetry via cyclic half-shell: o=(j-i) mod n, o in [1, n/2], weight 1/2 at
// o==n/2 -> exactly half the i!=j sum for BOTH eps-sum and count.
//
// Deep blocks win (r5/r8 vs r4/r6: shallow blocks = 73us, deep = 41us), so:
// 1024 blocks, each covers an 8-row strip x full o-range. Rows are split
// 2-per-wave (named scalars) to cut per-thread VGPR ~128 -> ~60, raising the
// wave/SIMD cap from 4 to 6 (launch_bounds (256,6); (256,8) spilled in r7).
// Each wave sweeps o in 33 wave-tiles of 64 (o<2112; o-r>2048 dead zone
// skipped entirely). No in-loop barriers; waves share j-lines via L1.

#define NRES 4096
#define NBATCH 2
#define TI 8
#define NTW 33             // wave-tiles of 64 lanes: o in [0, 2112)
#define NBLOCKS 1024       // 512 strips * 2 batches

// scaled cutoffs: 15*log2(e), 30*log2(e)
#define CUT15 21.6404256133f
#define CUT30 43.2808512267f

// Q coefficients: elementary symmetric polys of {e^0.5, e^1, e^2, e^4}
#define S1 66.35420923f
#define S2 678.60880385f
#define S3 2039.58217570f
#define S4 1808.04241445f
// Q'(t)/4 coefficients
#define QP1 16.58855231f
#define QP2 339.30440193f
#define QP3 1529.68663177f
#define QP4 1808.04241445f

#define LOG2E 1.44269504089f

__global__ void pack_kernel(const float* __restrict__ pred,
                            const float* __restrict__ truec,
                            const int* __restrict__ dna,
                            const int* __restrict__ rna,
                            const int* __restrict__ cm,
                            float4* __restrict__ tp,
                            float4* __restrict__ pp)
{
    int idx = blockIdx.x * 256 + threadIdx.x;
    if (idx >= NRES * NBATCH) return;
    float nuc = ((dna[idx] | rna[idx]) != 0) ? 1.0f : 0.0f;
    float cmf = (cm[idx] != 0) ? 1.0f : 0.0f;
    tp[idx] = make_float4(truec[3*idx+0]*LOG2E, truec[3*idx+1]*LOG2E, truec[3*idx+2]*LOG2E, nuc);
    pp[idx] = make_float4(pred[3*idx+0]*LOG2E,  pred[3*idx+1]*LOG2E,  pred[3*idx+2]*LOG2E,  cmf);
}

// one pair eval for one strip row; MODE 0: interior tile, 1: lower edge
// (need o > r), 2: upper edge (need o-r <= 2048, half weight at == 2048)
#define EVAL_ROW(TX,TY,TZ,PX,PY,PZ,CHI,CLO,RREL,MODE)                       \
    {                                                                       \
        float dx = TX - t4.x, dy = TY - t4.y, dz = TZ - t4.z;               \
        float dt = __builtin_amdgcn_sqrtf(dx*dx + dy*dy + dz*dz);           \
        float ex = PX - p4.x, ey = PY - p4.y, ez = PZ - p4.z;               \
        float dp = __builtin_amdgcn_sqrtf(ex*ex + ey*ey + ez*ez);           \
        float cutoff = nucj ? CHI : CLO;                                    \
        float mf = (dt < cutoff) ? wj : 0.0f;                               \
        if (MODE == 1) mf = (o > RREL) ? mf : 0.0f;                         \
        if (MODE == 2) { int d = o - RREL;                                  \
            mf = (d <= 2048) ? mf : 0.0f;                                   \
            mf = (d == 2048) ? 0.5f * mf : mf; }                            \
        float t = __builtin_amdgcn_exp2f(-fabsf(dt - dp));                  \
        float Q  = 1.0f + t*(S1 + t*(S2 + t*(S3 + t*S4)));                  \
        float Qp = QP1 + t*(QP2 + t*(QP3 + t*QP4));                         \
        float rq = __builtin_amdgcn_rcpf(Q);                                \
        s += mf * ((t * Qp) * rq);                                          \
        c += mf;                                                            \
    }

#define TILE_BODY(MODE)                                                     \
    EVAL_ROW(tAx,tAy,tAz,pAx,pAy,pAz,cHiA,cLoA,rA,MODE)                     \
    EVAL_ROW(tBx,tBy,tBz,pBx,pBy,pBz,cHiB,cLoB,rB,MODE)

__launch_bounds__(256, 6)
__global__ void lddt_main(const float4* __restrict__ tp,
                          const float4* __restrict__ pp,
                          float* __restrict__ acc,          // [0..1] sums, [2..3] counts
                          unsigned int* __restrict__ done,  // block-completion counter
                          float* __restrict__ out)
{
    const int b    = blockIdx.y;
    const int i0   = blockIdx.x * TI;
    const int base = b * NRES;
    const int tid  = threadIdx.x;
    const int wid  = tid >> 6;
    const int lane = tid & 63;

    // this wave's two strip rows (relative indices rA=2w, rB=2w+1)
    const int rA = 2 * wid;
    const int rB = rA + 1;

    float4 tA4 = tp[base + i0 + rA];
    float4 pA4 = pp[base + i0 + rA];
    float4 tB4 = tp[base + i0 + rB];
    float4 pB4 = pp[base + i0 + rB];

    const float tAx = tA4.x, tAy = tA4.y, tAz = tA4.z;
    const float pAx = pA4.x, pAy = pA4.y, pAz = pA4.z;
    const float tBx = tB4.x, tBy = tB4.y, tBz = tB4.z;
    const float pBx = pB4.x, pBy = pB4.y, pBz = pB4.z;

    const bool cmA  = (pA4.w != 0.0f), nucA = (tA4.w != 0.0f);
    const bool cmB  = (pB4.w != 0.0f), nucB = (tB4.w != 0.0f);
    const float cHiA = cmA ? (nucA ? CUT30 : CUT15) : -1.0f;
    const float cLoA = cmA ? CUT15 : -1.0f;
    const float cHiB = cmB ? (nucB ? CUT30 : CUT15) : -1.0f;
    const float cLoB = cmB ? CUT15 : -1.0f;

    float s = 0.0f, c = 0.0f;

    float4 t4 = tp[base + ((i0 + lane) & (NRES - 1))];
    float4 p4 = pp[base + ((i0 + lane) & (NRES - 1))];

    #pragma unroll 1
    for (int tl = 0; tl < NTW; ++tl) {
        // prefetch next wave-tile (last iter re-fetches tile 0; in-bounds)
        const int on = ((tl + 1 < NTW) ? tl + 1 : 0) * 64 + lane;
        const int jn = (i0 + on) & (NRES - 1);
        float4 t4n = tp[base + jn];
        float4 p4n = pp[base + jn];

        const float wj   = p4.w;              // cm_j as 1.0/0.0
        const bool  nucj = (t4.w != 0.0f);
        const int   o    = (tl << 6) + lane;  // cyclic offset j-i0

        if (tl == 0)            { TILE_BODY(1) }
        else if (tl == NTW - 1) { TILE_BODY(2) }
        else                    { TILE_BODY(0) }

        t4 = t4n; p4 = p4n;
    }

    // wave (64-lane) reduction
    #pragma unroll
    for (int off = 32; off > 0; off >>= 1) {
        s += __shfl_down(s, off, 64);
        c += __shfl_down(c, off, 64);
    }

    __shared__ float red_s[4];
    __shared__ float red_c[4];
    if (lane == 0) { red_s[wid] = s; red_c[wid] = c; }
    __syncthreads();

    if (tid == 0) {
        float ts = red_s[0] + red_s[1] + red_s[2] + red_s[3];
        float tc = red_c[0] + red_c[1] + red_c[2] + red_c[3];
        atomicAdd(&acc[b], ts);
        atomicAdd(&acc[NBATCH + b], tc);
        __threadfence();
        unsigned int old = atomicAdd(done, 1u);
        if (old == NBLOCKS - 1u) {
            float a0 = __hip_atomic_load(&acc[0], __ATOMIC_ACQUIRE, __HIP_MEMORY_SCOPE_AGENT);
            float a1 = __hip_atomic_load(&acc[1], __ATOMIC_ACQUIRE, __HIP_MEMORY_SCOPE_AGENT);
            float c0 = __hip_atomic_load(&acc[2], __ATOMIC_ACQUIRE, __HIP_MEMORY_SCOPE_AGENT);
            float c1 = __hip_atomic_load(&acc[3], __ATOMIC_ACQUIRE, __HIP_MEMORY_SCOPE_AGENT);
            float l0 = a0 / fmaxf(c0, 0.5f);
            float l1 = a1 / fmaxf(c1, 0.5f);
            out[0] = 1.0f - 0.5f * (l0 + l1);
        }
    }
}

extern "C" void kernel_launch(void* const* d_in, const int* in_sizes, int n_in,
                              void* d_out, int out_size, void* d_ws, size_t ws_size,
                              hipStream_t stream) {
    const float* pred  = (const float*)d_in[0];
    const float* truec = (const float*)d_in[1];
    const int*   dna   = (const int*)d_in[2];
    const int*   rna   = (const int*)d_in[3];
    const int*   cmask = (const int*)d_in[4];
    float* out = (float*)d_out;

    char* ws = (char*)d_ws;
    float*        acc  = (float*)ws;              // 4 floats
    unsigned int* done = (unsigned int*)(ws + 64);
    float4* tp = (float4*)(ws + 1024);            // 2*4096*16 B
    float4* pp = (float4*)(ws + 1024 + NBATCH*NRES*16);

    (void)hipMemsetAsync(ws, 0, 128, stream);     // acc + done

    pack_kernel<<<(NRES*NBATCH + 255)/256, 256, 0, stream>>>(pred, truec, dna, rna, cmask, tp, pp);

    dim3 grid(NRES / TI, NBATCH);
    lddt_main<<<grid, 256, 0, stream>>>(tp, pp, acc, done, out);
}